// Round 8
// baseline (3513.115 us; speedup 1.0000x reference)
//
#include <hip/hip_runtime.h>
#include <hip/hip_bf16.h>

// 2-layer GRU decoder, persistent MFMA kernel. B=128, T=1024, H=200.
// R8 = R7 EXACT (8 groups x 16 slices = 128 blocks, NB=16, hBh/hBl[st][b][k]
// LDS planes, flag-line sync) with ONE change: global h exchange buffers are
// TRANSPOSED to [k][b] (h0g[2][200][128]). Gate stores (cj=tid>>4, cb=tid&15)
// now write 4 FULL 64B lines per instruction instead of 16B fragments of 16
// lines -> no partial-line write-through RMW. R7 counters showed 3x HBM write
// amplification (WRITE 653 MB vs 227 MB useful) and the per-step vmcnt(0)
// drain waits on those scattered write-acks.

#define TT 1024
#define HH 200
#define NB 16
#define HS 13
#define KP 232      // LDS hB row stride in ushorts; 464 B = 29*16 -> b128-aligned
#define HBUF 25600  // one h buffer: 200 k x 128 b u32

typedef __attribute__((ext_vector_type(8))) short short8;
typedef __attribute__((ext_vector_type(4))) float f32x4;

__device__ __forceinline__ float sigm(float v) { return 1.0f / (1.0f + __expf(-v)); }
__device__ __forceinline__ float tanh_fast(float v) {
  float e = __expf(-2.0f * v);
  return (1.0f - e) / (1.0f + e);
}
__device__ __forceinline__ uint llc_load_u32(const uint* p) {
  return __hip_atomic_load(p, __ATOMIC_RELAXED, __HIP_MEMORY_SCOPE_SYSTEM);
}
__device__ __forceinline__ void llc_store_u32(uint* p, uint v) {
  __hip_atomic_store(p, v, __ATOMIC_RELAXED, __HIP_MEMORY_SCOPE_SYSTEM);
}
__device__ __forceinline__ float bfu2f(ushort u) { return __uint_as_float(((uint)u) << 16); }
__device__ __forceinline__ ushort f2bfu(float f) {
  __hip_bfloat16 b = __float2bfloat16(f);
  return *(ushort*)&b;
}
__device__ __forceinline__ uint packf(float h) {
  ushort hi = f2bfu(h);
  ushort lo = f2bfu(h - bfu2f(hi));
  return (uint)hi | (((uint)lo) << 16);
}

__global__ __launch_bounds__(256, 1) void gru2_mfma(
    const float* __restrict__ x,
    const float* __restrict__ Wih0, const float* __restrict__ Whh0,
    const float* __restrict__ bih0, const float* __restrict__ bhh0,
    const float* __restrict__ Wih1, const float* __restrict__ Whh1,
    const float* __restrict__ bih1, const float* __restrict__ bhh1,
    const float* __restrict__ Wfc,  const float* __restrict__ bfc,
    float* __restrict__ out,
    uint* __restrict__ h0g, uint* __restrict__ h1g, uint* __restrict__ flags)
{
  __shared__ __align__(16) ushort hBh[2][NB][KP];
  __shared__ __align__(16) ushort hBl[2][NB][KP];
  __shared__ float D[117][17];
  __shared__ float Wi0[39][8];
  __shared__ float bi0[39], bh0[39], bi1[39], bh1[39], bfs[4];
  __shared__ float xc[NB][8];

  const int tid  = threadIdx.x;
  const int wave = tid >> 6;
  const int lane = tid & 63;
  const int m15  = lane & 15;
  const int q    = lane >> 4;

  const int g  = blockIdx.x & 7;    // batch-group
  const int s  = blockIdx.x >> 3;   // hidden-slice
  const int b0 = g * NB;
  const int j0 = s * HS;
  const int hs = (HH - j0 < HS) ? (HH - j0) : HS;   // 13 (s<15) or 5 (s==15)
  const int th   = 3 * hs;
  const int h0r  = 6 * hs;                          // rows dotted with h0
  const int T0   = (h0r + 15) >> 4;                 // 5 or 2  (h0 tiles)
  const int NT   = T0 + ((th + 15) >> 4);           // 8 or 3  (total tiles)
  const bool isOut = (s == 15);

  // ---- one-time: weight A-fragments into registers (hi/lo bf16) ----
  short8 Ah[2][7], Al[2][7];
  #pragma unroll
  for (int mt = 0; mt < 2; ++mt) {
    const int T = wave * 2 + mt;
    const bool fc  = isOut && (wave == 2) && (mt == 0);
    const bool val = fc || (T < NT);
    #pragma unroll
    for (int kt = 0; kt < 7; ++kt) {
      short8 vh = {0,0,0,0,0,0,0,0}, vl = {0,0,0,0,0,0,0,0};
      #pragma unroll
      for (int j = 0; j < 8; ++j) {
        const int k = kt * 32 + q * 8 + j;
        float w = 0.0f;
        if (val && k < HH) {
          if (fc) {
            if (m15 < 4) w = Wfc[m15 * HH + k];
          } else {
            const int p = T * 16 + m15;
            int r = -1;
            if (p < h0r) r = p;
            else if (p >= T0 * 16 && (p - T0 * 16) < th) r = h0r + (p - T0 * 16);
            if (r >= 0) {
              const int m  = r / th, rr = r - m * th;
              const int qq = rr / hs, jj = rr - qq * hs;
              const float* src = (m == 0) ? Whh0 : ((m == 1) ? Wih1 : Whh1);
              w = src[(qq * HH + j0 + jj) * HH + k];
            }
          }
        }
        const ushort uh = f2bfu(w);
        const ushort ul = f2bfu(w - bfu2f(uh));
        vh[j] = (short)uh; vl[j] = (short)ul;
      }
      Ah[mt][kt] = vh; Al[mt][kt] = vl;
    }
  }

  // ---- one-time: small LDS tables ----
  for (int u = tid; u < th * 8; u += 256) {
    int rr = u >> 3, c = u & 7;
    int qq = rr / hs, jj = rr - qq * hs;
    Wi0[rr][c] = Wih0[(qq * HH + j0 + jj) * 8 + c];
  }
  for (int u = tid; u < th; u += 256) {
    int qq = u / hs, jj = u - qq * hs;
    int grow = qq * HH + j0 + jj;
    bi0[u] = bih0[grow]; bh0[u] = bhh0[grow];
    bi1[u] = bih1[grow]; bh1[u] = bhh1[grow];
  }
  if (tid < 4) bfs[tid] = bfc[tid];
  for (int u = tid; u < 2 * NB * KP / 2; u += 256) ((uint*)hBh)[u] = 0;  // zero pads
  for (int u = tid; u < 2 * NB * KP / 2; u += 256) ((uint*)hBl)[u] = 0;
  __syncthreads();

  // ---- staging map precompute: u = tid + 256*i over [0,6400) ----
  // Global layout is now [k][b]: st = u/3200, k = rem>>4, b = rem&15.
  // Per wave-instruction: 4 k-rows x 16 b = 4 full 64B lines (coalesced).
  // LDS write banks: k,k+1 pairs share a dword -> ~2-way (free).
  int boff[25], lofs[25]; uint stm = 0;
  #pragma unroll
  for (int i = 0; i < 25; ++i) {
    const int u   = tid + i * 256;
    const int st  = (u >= 3200) ? 1 : 0;
    const int rem = u - st * 3200;
    const int k   = rem >> 4;
    const int b   = rem & 15;
    boff[i] = k * 128 + b0 + b;
    lofs[i] = (st * NB + b) * KP + k;
    if (st) stm |= (1u << i);
  }
  ushort* const hBhF = &hBh[0][0][0];
  ushort* const hBlF = &hBl[0][0][0];

  uint* const flg = flags + g * 32;   // 16 flags in one 64B line; 128B group stride
  const int cj = tid >> 4, cb = tid & 15;   // gate-combine indices

  for (int t = 0; t <= TT + 1; ++t) {
    // ---- x(t) staging first (flag-independent; overlaps the poll) ----
    if (tid < 128 && t < TT) {
      int b = tid >> 3, c = tid & 7;
      float xv;
      if (c < 4) xv = (t == 0) ? 1.0f : x[((b0 + b) * TT + (t - 1)) * 8 + c];
      else       xv = x[(b0 + b) * TT * 8 + c];
      xc[b][c] = xv;
    }

    // ---- wait: all 16 producer flags >= t (no RMW, one 64B line) ----
    if (wave == 0) {
      const uint tgt = (uint)t;
      for (;;) {
        uint f = tgt;
        if (lane < 16) f = llc_load_u32(flg + lane);
        if (__all((int)(f >= tgt))) break;
        __builtin_amdgcn_s_sleep(1);
      }
    }
    __syncthreads();

    // ---- stage h0(t-1), h1(t-2): packed bf16 hi/lo from LLC -> LDS planes ----
    const uint* h0src = h0g + ((t + 1) & 1) * HBUF;
    const uint* h1src = h1g + (t & 1) * HBUF;
    uint v[25];
    #pragma unroll
    for (int i = 0; i < 25; ++i)
      v[i] = llc_load_u32((((stm >> i) & 1) ? h1src : h0src) + boff[i]);
    #pragma unroll
    for (int i = 0; i < 25; ++i) {
      hBhF[lofs[i]] = (ushort)(v[i] & 0xffffu);
      hBlF[lofs[i]] = (ushort)(v[i] >> 16);
    }
    __syncthreads();   // bar1

    // ---- MFMA: D[rows x 16 batch] = W * h, bf16x3; B shared per st ----
    {
      const int  Ta = 2 * wave, Tb = Ta + 1;
      const bool fa = isOut && (wave == 2);        // FC tile = wave2/mt0
      const bool va = (Ta < NT) || fa;
      const bool vb = (Tb < NT);
      const int  sa = fa ? 1 : ((Ta < T0) ? 0 : 1);
      const int  sb = (Tb < T0) ? 0 : 1;
      f32x4 acc0 = {0.f,0.f,0.f,0.f}, acc1 = {0.f,0.f,0.f,0.f};
      #pragma unroll
      for (int st = 0; st < 2; ++st) {
        const bool nA = va && (sa == st), nB = vb && (sb == st);
        if (!(nA || nB)) continue;
        const ushort* bh = &hBh[st][m15][0];
        const ushort* bl = &hBl[st][m15][0];
        #pragma unroll
        for (int kt = 0; kt < 7; ++kt) {
          const short8 Bh = *(const short8*)(bh + kt * 32 + q * 8);
          const short8 Bl = *(const short8*)(bl + kt * 32 + q * 8);
          if (nA) {
            acc0 = __builtin_amdgcn_mfma_f32_16x16x32_bf16(Ah[0][kt], Bh, acc0, 0, 0, 0);
            acc0 = __builtin_amdgcn_mfma_f32_16x16x32_bf16(Ah[0][kt], Bl, acc0, 0, 0, 0);
            acc0 = __builtin_amdgcn_mfma_f32_16x16x32_bf16(Al[0][kt], Bh, acc0, 0, 0, 0);
          }
          if (nB) {
            acc1 = __builtin_amdgcn_mfma_f32_16x16x32_bf16(Ah[1][kt], Bh, acc1, 0, 0, 0);
            acc1 = __builtin_amdgcn_mfma_f32_16x16x32_bf16(Ah[1][kt], Bl, acc1, 0, 0, 0);
            acc1 = __builtin_amdgcn_mfma_f32_16x16x32_bf16(Al[1][kt], Bh, acc1, 0, 0, 0);
          }
        }
      }
      if (fa) {                              // FC head: out(t-2)
        if (t >= 2) {
          #pragma unroll
          for (int i = 0; i < 4; ++i) {
            const int p = q * 4 + i;
            if (p < 4)
              out[((b0 + m15) * TT + (t - 2)) * 4 + p] = tanh_fast(acc0[i] + bfs[p]);
          }
        }
      } else if (va) {
        #pragma unroll
        for (int i = 0; i < 4; ++i) {
          const int p = Ta * 16 + q * 4 + i;
          int r = -1;
          if (p < h0r) r = p;
          else if (p >= T0 * 16 && (p - T0 * 16) < th) r = h0r + (p - T0 * 16);
          if (r >= 0) D[r][m15] = acc0[i];
        }
      }
      if (vb) {
        #pragma unroll
        for (int i = 0; i < 4; ++i) {
          const int p = Tb * 16 + q * 4 + i;
          int r = -1;
          if (p < h0r) r = p;
          else if (p >= T0 * 16 && (p - T0 * 16) < th) r = h0r + (p - T0 * 16);
          if (r >= 0) D[r][m15] = acc1[i];
        }
      }
    }
    __syncthreads();   // bar2

    // ---- gate combine + state update; stores hit FULL 64B lines ([k][b]) ----
    if (cj < hs) {
      const float hv0 = bfu2f(hBh[0][cb][j0 + cj]) + bfu2f(hBl[0][cb][j0 + cj]);
      const float hv1 = bfu2f(hBh[1][cb][j0 + cj]) + bfu2f(hBl[1][cb][j0 + cj]);
      if (t < TT) {                 // h0(t)
        float ir = bi0[cj], iz = bi0[hs + cj], in_ = bi0[2 * hs + cj];
        #pragma unroll
        for (int c = 0; c < 8; ++c) {
          const float xv = xc[cb][c];
          ir  += Wi0[cj][c] * xv;
          iz  += Wi0[hs + cj][c] * xv;
          in_ += Wi0[2 * hs + cj][c] * xv;
        }
        const float hr = D[cj][cb] + bh0[cj];
        const float hz = D[hs + cj][cb] + bh0[hs + cj];
        const float hn = D[2 * hs + cj][cb] + bh0[2 * hs + cj];
        const float r = sigm(ir + hr), z = sigm(iz + hz);
        const float n = tanh_fast(in_ + r * hn);
        llc_store_u32(&h0g[(t & 1) * HBUF + (j0 + cj) * 128 + (b0 + cb)],
                      packf((1.0f - z) * n + z * hv0));
      }
      if (t >= 1 && t <= TT) {      // h1(t-1)
        const float ir  = D[3 * hs + cj][cb] + bi1[cj];
        const float iz  = D[4 * hs + cj][cb] + bi1[hs + cj];
        const float in_ = D[5 * hs + cj][cb] + bi1[2 * hs + cj];
        const float hr  = D[6 * hs + cj][cb] + bh1[cj];
        const float hz  = D[7 * hs + cj][cb] + bh1[hs + cj];
        const float hn  = D[8 * hs + cj][cb] + bh1[2 * hs + cj];
        const float r = sigm(ir + hr), z = sigm(iz + hz);
        const float n = tanh_fast(in_ + r * hn);
        llc_store_u32(&h1g[((t + 1) & 1) * HBUF + (j0 + cj) * 128 + (b0 + cb)],
                      packf((1.0f - z) * n + z * hv1));
      }
    }

    // ---- signal: drain stores (syncthreads waits vmcnt(0)), then flag=t+1 ----
    __syncthreads();
    if (tid == 0) llc_store_u32(flg + s, (uint)(t + 1));
  }
}

extern "C" void kernel_launch(void* const* d_in, const int* in_sizes, int n_in,
                              void* d_out, int out_size, void* d_ws, size_t ws_size,
                              hipStream_t stream) {
  uint* ws = (uint*)d_ws;
  // ws (u32): h0g[2][200][128] @0, h1g[2][200][128] @51200,
  // flags (8 groups x 32 u32 stride, 16 used each) @102400. memset -> h=0, flags=0.
  hipMemsetAsync(d_ws, 0, (size_t)(102400 + 512) * sizeof(uint), stream);
  gru2_mfma<<<128, 256, 0, stream>>>(
      (const float*)d_in[0],
      (const float*)d_in[1], (const float*)d_in[2],
      (const float*)d_in[3], (const float*)d_in[4],
      (const float*)d_in[5], (const float*)d_in[6],
      (const float*)d_in[7], (const float*)d_in[8],
      (const float*)d_in[9], (const float*)d_in[10],
      (float*)d_out, ws, ws + 51200, ws + 102400);
}